// Round 1
// 547.107 us; speedup vs baseline: 1.2369x; 1.2369x over previous
//
#include <hip/hip_runtime.h>
#include <hip/hip_bf16.h>
#include <stdint.h>

typedef short bf16x8 __attribute__((ext_vector_type(8)));
typedef float f32x4  __attribute__((ext_vector_type(4)));

#define NNODES    32768
#define KNB       16
#define FDIM      128
#define NEG_SLOPE 0.2f
#define NBLK      512                      // persistent blocks (2 per CU)
#define PPB       (NNODES / (2 * NBLK))    // 32 node-pairs per block

// fp32 -> bf16 round-to-nearest-even (scalar; prep only)
static __device__ __forceinline__ unsigned short f2bf(float x) {
  union { float f; unsigned u; } v; v.f = x;
  unsigned r = v.u + 0x7fffu + ((v.u >> 16) & 1u);
  return (unsigned short)(r >> 16);
}

// packed HW conversion: 8 fp32 -> bf16x8
static __device__ __forceinline__ bf16x8 pack8(f32x4 lo, f32x4 hi) {
  union { __hip_bfloat162 h[4]; bf16x8 v; } u;
  u.h[0] = __float22bfloat162_rn(make_float2(lo[0], lo[1]));
  u.h[1] = __float22bfloat162_rn(make_float2(lo[2], lo[3]));
  u.h[2] = __float22bfloat162_rn(make_float2(hi[0], hi[1]));
  u.h[3] = __float22bfloat162_rn(make_float2(hi[2], hi[3]));
  return u.v;
}

// ---------------------------------------------------------------------------
// Prep: fragment-linear B.  BL[((kc*8 + ct)*64 + quad*16 + l16)*8 + j]
//   = B[o = ct*16 + l16][f = kc*32 + quad*8 + j],  f in [0,384) = [M1|M2|W].
// A wave owning column-tile ct loads frag kc as ONE contiguous 1KB read.
// ---------------------------------------------------------------------------
static __device__ __forceinline__ void storeBL(unsigned short* BL, int ct, int l16,
                                               int col, unsigned short v) {
  const int kc = col >> 5, quad = (col >> 3) & 3, j = col & 7;
  BL[(size_t)(((kc * 8 + ct) * 64) + quad * 16 + l16) * 8 + j] = v;
}

__global__ void prep_weights(const float* __restrict__ W,
                             const float* __restrict__ Wa,
                             unsigned short* __restrict__ BL) {
  const int o = blockIdx.x;    // 0..127 output col
  const int f = threadIdx.x;   // 0..127
  const float* war = Wa + o * 256;
  float a1 = 0.f, a2 = 0.f;
  #pragma unroll 8
  for (int j = 0; j < 128; ++j) {
    float w = W[j * 128 + f];                // coalesced across threads
    a1 = fmaf(war[j], w, a1);
    a2 = fmaf(war[128 + j], w, a2);
  }
  const int ct = o >> 4, l16 = o & 15;
  storeBL(BL, ct, l16, f,       f2bf(a1));
  storeBL(BL, ct, l16, 128 + f, f2bf(a2));
  storeBL(BL, ct, l16, 256 + f, f2bf(W[o * 128 + f]));
}

// ---------------------------------------------------------------------------
// Main: 8 waves/block, wave w owns output col-tile ct=w (B = 12 frags in regs,
// loaded ONCE).  Per iteration: one node-pair; A (neighbors|aspects) staged
// fp32->bf16 into double-buffered, XOR-swizzled LDS; next pair's global loads
// issued at iteration top so HBM latency hides under compute (2-phase
// pipeline, 2 blocks/CU antiphase).
// ---------------------------------------------------------------------------
__global__ __launch_bounds__(512, 4)
void grn_main(const float* __restrict__ nodes,
              const float* __restrict__ neighbors,
              const float* __restrict__ aspects,
              const float* __restrict__ scores,
              const unsigned short* __restrict__ BL,
              const float* __restrict__ ba,
              const float* __restrict__ bias,
              float* __restrict__ out) {
  const int tid  = threadIdx.x;
  const int lane = tid & 63;
  const int w    = tid >> 6;     // wave id == ct (output col tile)
  const int quad = lane >> 4;
  const int l16  = lane & 15;

  // LDS: edge A tiles (2 nodes x 16 rows x 256 cols bf16 = 16KB), dbuf;
  //      node chunks (2 x 128 bf16 = 512B), dbuf; epilogue transpose, dbuf.
  __shared__ __align__(16) unsigned short Aeg[2][8192];
  __shared__ __align__(16) unsigned short And[2][256];
  __shared__ float xp[2][2][FDIM];

  // ---- B fragments: resident in registers for the whole kernel (48 VGPR)
  bf16x8 breg[12];
  #pragma unroll
  for (int kc = 0; kc < 12; ++kc)
    breg[kc] = *(const bf16x8*)(BL + ((size_t)(kc * 8 + w) * 64 + lane) * 8);

  const float ba_c = ba[w * 16 + l16];
  float bias_t = 0.f;
  if (tid < 256) bias_t = bias[tid & 127];

  // ---- staging decode (edge): thread owns chunk (seg,row,c16) for n=0,1
  const int seg = tid >> 8;            // 0: neighbors, 1: aspects
  const int row = (tid >> 4) & 15;     // edge index 0..15
  const int c16 = tid & 15;            // 8-float chunk within the 128 cols
  const int cc  = seg * 16 + c16;      // chunk 0..31 within 256-col row
  const float* segp = seg ? aspects : neighbors;
  // write byte offset within one node half (XOR swizzle, G4 pattern)
  const int wroff = row * 512 + ((cc * 16) ^ ((row & 7) << 4));
  // read-side per-lane constants
  const int sw    = (l16 & 7) << 4;
  const int rdrow = l16 * 512;

  const int pair0 = blockIdx.x * PPB;

  f32x4 eg[2][2];   // in-flight edge fp32 (2 chunks x 8 floats)
  f32x4 nd[2];      // in-flight node fp32 (tid<32 only)

  // ---- prologue: stage pair0 into buf 0
  {
    const size_t ng = (size_t)pair0 * 2;
    #pragma unroll
    for (int n = 0; n < 2; ++n) {
      const float* src = segp + ((ng + n) * KNB + row) * FDIM + c16 * 8;
      eg[n][0] = *(const f32x4*)src;
      eg[n][1] = *(const f32x4*)(src + 4);
    }
    if (tid < 32) {
      const float* nsrc = nodes + (ng + (tid >> 4)) * FDIM + (tid & 15) * 8;
      nd[0] = *(const f32x4*)nsrc;
      nd[1] = *(const f32x4*)(nsrc + 4);
    }
    #pragma unroll
    for (int n = 0; n < 2; ++n)
      *(bf16x8*)((char*)Aeg[0] + n * 8192 + wroff) = pack8(eg[n][0], eg[n][1]);
    if (tid < 32)
      *(bf16x8*)((char*)And[0] + tid * 16) = pack8(nd[0], nd[1]);
  }
  __syncthreads();

  for (int i = 0; i < PPB; ++i) {
    const int buf = i & 1;
    const size_t ng = (size_t)(pair0 + i) * 2;

    // ---- issue next pair's global loads (in flight across compute)
    if (i + 1 < PPB) {
      const size_t ng2 = ng + 2;
      #pragma unroll
      for (int n = 0; n < 2; ++n) {
        const float* src = segp + ((ng2 + n) * KNB + row) * FDIM + c16 * 8;
        eg[n][0] = *(const f32x4*)src;
        eg[n][1] = *(const f32x4*)(src + 4);
      }
      if (tid < 32) {
        const float* nsrc = nodes + (ng2 + (tid >> 4)) * FDIM + (tid & 15) * 8;
        nd[0] = *(const f32x4*)nsrc;
        nd[1] = *(const f32x4*)(nsrc + 4);
      }
    }

    // ---- compute: D[16 edges x 16 cols] per node, K = 384
    f32x4 acc[2];
    acc[0] = (f32x4){0.f, 0.f, 0.f, 0.f};
    acc[1] = (f32x4){0.f, 0.f, 0.f, 0.f};
    const char* ab = (const char*)Aeg[buf];
    const char* nb = (const char*)And[buf];
    #pragma unroll
    for (int n = 0; n < 2; ++n) {
      #pragma unroll
      for (int kc = 0; kc < 8; ++kc) {       // edge cols 0..255
        bf16x8 af = *(const bf16x8*)(ab + n * 8192 + rdrow +
                                     (((kc * 4 + quad) * 16) ^ sw));
        acc[n] = __builtin_amdgcn_mfma_f32_16x16x32_bf16(af, breg[kc], acc[n], 0, 0, 0);
      }
      #pragma unroll
      for (int kn = 0; kn < 4; ++kn) {       // node cols 256..383 (broadcast rows)
        bf16x8 af = *(const bf16x8*)(nb + (n * 16 + kn * 4 + quad) * 16);
        acc[n] = __builtin_amdgcn_mfma_f32_16x16x32_bf16(af, breg[8 + kn], acc[n], 0, 0, 0);
      }
    }

    // ---- epilogue: per-edge exp(lrelu) * score, k-reduce via shfl
    #pragma unroll
    for (int n = 0; n < 2; ++n) {
      f32x4 sc = *(const f32x4*)(scores + (ng + n) * KNB + quad * 4);
      float s = 0.f;
      #pragma unroll
      for (int r = 0; r < 4; ++r) {
        float t  = acc[n][r] + ba_c;
        float lr = t > 0.f ? t : NEG_SLOPE * t;
        s = fmaf(__expf(lr), sc[r], s);
      }
      s += __shfl_xor(s, 16);
      s += __shfl_xor(s, 32);
      if (quad == 0) xp[buf][n][w * 16 + l16] = s;
    }

    // ---- convert + write next pair's staging into the other buffer
    if (i + 1 < PPB) {
      const int nbuf = buf ^ 1;
      #pragma unroll
      for (int n = 0; n < 2; ++n)
        *(bf16x8*)((char*)Aeg[nbuf] + n * 8192 + wroff) = pack8(eg[n][0], eg[n][1]);
      if (tid < 32)
        *(bf16x8*)((char*)And[nbuf] + tid * 16) = pack8(nd[0], nd[1]);
    }
    __syncthreads();

    // ---- output store (xp[buf] valid after barrier; 512B coalesced/node)
    if (tid < 256) {
      const int n = tid >> 7, c = tid & 127;
      float v = xp[buf][n][c] + bias_t;
      v = v > 0.f ? v : __expf(v) - 1.f;
      out[(ng + n) * FDIM + c] = v;
    }
  }
}

extern "C" void kernel_launch(void* const* d_in, const int* in_sizes, int n_in,
                              void* d_out, int out_size, void* d_ws, size_t ws_size,
                              hipStream_t stream) {
  const float* nodes     = (const float*)d_in[0];
  const float* neighbors = (const float*)d_in[1];
  const float* aspects   = (const float*)d_in[2];
  const float* scores    = (const float*)d_in[3];
  const float* W         = (const float*)d_in[4];
  const float* Wa        = (const float*)d_in[5];
  const float* ba        = (const float*)d_in[6];
  const float* bias      = (const float*)d_in[7];
  unsigned short* BL     = (unsigned short*)d_ws;   // 12*8*64*8*2B = 96 KB

  prep_weights<<<128, 128, 0, stream>>>(W, Wa, BL);
  grn_main<<<NBLK, 512, 0, stream>>>(nodes, neighbors, aspects, scores,
                                     BL, ba, bias, (float*)d_out);
}